// Round 1
// baseline (1458.322 us; speedup 1.0000x reference)
//
#include <hip/hip_runtime.h>
#include <stdint.h>

// Problem constants (from reference)
#define NS   65536    // SAMPLES
#define XD   128      // LX*DX
#define ZD   128      // LZ*DZ
// n states = 4

// ---------------- threefry2x32 (exact JAX semantics) ----------------
struct U2 { uint32_t x, y; };

__host__ __device__ constexpr uint32_t rotl32(uint32_t v, int r) {
  return (v << r) | (v >> (32 - r));
}

__host__ __device__ constexpr U2 threefry2x32(uint32_t k0, uint32_t k1,
                                              uint32_t x0, uint32_t x1) {
  uint32_t ks0 = k0, ks1 = k1, ks2 = k0 ^ k1 ^ 0x1BD11BDAu;
  x0 += ks0; x1 += ks1;
  // group 1: rotations 13,15,26,6
  x0 += x1; x1 = rotl32(x1, 13); x1 ^= x0;
  x0 += x1; x1 = rotl32(x1, 15); x1 ^= x0;
  x0 += x1; x1 = rotl32(x1, 26); x1 ^= x0;
  x0 += x1; x1 = rotl32(x1,  6); x1 ^= x0;
  x0 += ks1; x1 += ks2 + 1u;
  // group 2: rotations 17,29,16,24
  x0 += x1; x1 = rotl32(x1, 17); x1 ^= x0;
  x0 += x1; x1 = rotl32(x1, 29); x1 ^= x0;
  x0 += x1; x1 = rotl32(x1, 16); x1 ^= x0;
  x0 += x1; x1 = rotl32(x1, 24); x1 ^= x0;
  x0 += ks2; x1 += ks0 + 2u;
  // group 3: rotations 13,15,26,6
  x0 += x1; x1 = rotl32(x1, 13); x1 ^= x0;
  x0 += x1; x1 = rotl32(x1, 15); x1 ^= x0;
  x0 += x1; x1 = rotl32(x1, 26); x1 ^= x0;
  x0 += x1; x1 = rotl32(x1,  6); x1 ^= x0;
  x0 += ks0; x1 += ks1 + 3u;
  // group 4: rotations 17,29,16,24
  x0 += x1; x1 = rotl32(x1, 17); x1 ^= x0;
  x0 += x1; x1 = rotl32(x1, 29); x1 ^= x0;
  x0 += x1; x1 = rotl32(x1, 16); x1 ^= x0;
  x0 += x1; x1 = rotl32(x1, 24); x1 ^= x0;
  x0 += ks1; x1 += ks2 + 4u;
  // group 5: rotations 13,15,26,6
  x0 += x1; x1 = rotl32(x1, 13); x1 ^= x0;
  x0 += x1; x1 = rotl32(x1, 15); x1 ^= x0;
  x0 += x1; x1 = rotl32(x1, 26); x1 ^= x0;
  x0 += x1; x1 = rotl32(x1,  6); x1 ^= x0;
  x0 += ks2; x1 += ks0 + 5u;
  return {x0, x1};
}

// jax.random.key(42) -> raw (0,42).
// split (partitionable/foldlike): keys[i] = threefry2x32(key, (0, i))
constexpr U2 KEYZ = threefry2x32(0u, 42u, 0u, 0u);
constexpr U2 KEYX = threefry2x32(0u, 42u, 0u, 1u);
constexpr uint32_t KZ0 = KEYZ.x, KZ1 = KEYZ.y;
constexpr uint32_t KX0 = KEYX.x, KX1 = KEYX.y;

// gumbel sample for flat index idx (32-bit path, partitionable bits = h1^h2)
__device__ inline double gumbel32(uint32_t k0, uint32_t k1, uint32_t idx) {
  U2 h = threefry2x32(k0, k1, 0u, idx);
  uint32_t bits = h.x ^ h.y;
  float f = __uint_as_float((bits >> 9) | 0x3f800000u) - 1.0f;  // [0,1)
  float u = (f == 0.0f) ? 1.1754943508222875e-38f : f;          // max(tiny, .)
  double lu = log((double)u);        // < 0
  return -log(-lu);
}

// ---------------- kernel 0: pack x0_idx to 2-bit codes, zero loss ----------------
__global__ __launch_bounds__(256) void pack_x0(const int* __restrict__ x0,
                                               uint32_t* __restrict__ pk,
                                               double* __restrict__ loss_acc) {
  int t = blockIdx.x * 256 + threadIdx.x;   // 0 .. NS*8-1
  if (t == 0) *loss_acc = 0.0;
  const int4* src = (const int4*)x0 + (size_t)t * 4;  // 16 consecutive ints
  uint32_t w = 0;
#pragma unroll
  for (int i = 0; i < 4; ++i) {
    int4 v = src[i];
    w |= (uint32_t)(v.x & 3) << (8 * i + 0);
    w |= (uint32_t)(v.y & 3) << (8 * i + 2);
    w |= (uint32_t)(v.z & 3) << (8 * i + 4);
    w |= (uint32_t)(v.w & 3) << (8 * i + 6);
  }
  pk[t] = w;
}

// ---------------- kernel 1: build K in two gather-friendly layouts ----------------
// K[x,z,p,q] = sum_k (sum_b biadj[ix,iz,b]*eps[b,k,dx,dz]) * chi[p,q,k]
// Kz[z][x][a][b] (float4 over b), Kx[x][z][b][a] (float4 over a)
__global__ __launch_bounds__(256) void build_k(const float* __restrict__ biadj,
                                               const float* __restrict__ eps,
                                               const float* __restrict__ chi,
                                               float* __restrict__ Kz,
                                               float* __restrict__ Kx) {
  int t = blockIdx.x * 256 + threadIdx.x;  // 0..16383
  int xx = t >> 7, zz = t & 127;
  int ix = xx >> 1, dx = xx & 1;
  int iz = zz >> 1, dz = zz & 1;
  double c0 = 0.0, c1 = 0.0, c2 = 0.0;
#pragma unroll
  for (int b = 0; b < 8; ++b) {
    double bi = (double)biadj[(ix * 64 + iz) * 8 + b];
    c0 += bi * (double)eps[((b * 3 + 0) * 2 + dx) * 2 + dz];
    c1 += bi * (double)eps[((b * 3 + 1) * 2 + dx) * 2 + dz];
    c2 += bi * (double)eps[((b * 3 + 2) * 2 + dx) * 2 + dz];
  }
#pragma unroll
  for (int p = 0; p < 4; ++p)
#pragma unroll
    for (int q = 0; q < 4; ++q) {
      double kv = c0 * (double)chi[(p * 4 + q) * 3 + 0]
                + c1 * (double)chi[(p * 4 + q) * 3 + 1]
                + c2 * (double)chi[(p * 4 + q) * 3 + 2];
      float kf = (float)kv;
      Kz[((zz * 128 + xx) * 4 + p) * 4 + q] = kf;
      Kx[((xx * 128 + zz) * 4 + q) * 4 + p] = kf;
    }
}

// ---------------- kernel 2: ez + categorical(kz) -> zidxT[z][s] ----------------
__global__ __launch_bounds__(256) void ez_sample(const float* __restrict__ Kz,
                                                 const uint32_t* __restrict__ pk,
                                                 uint8_t* __restrict__ zidxT) {
  int s = blockIdx.x * 256 + threadIdx.x;   // lane-major over s
  int z = blockIdx.y;
  const float4* kz = (const float4*)Kz + (size_t)z * 512;  // [x][a] float4 over b
  const uint32_t* pks = pk + (size_t)s * 8;
  double a0 = 0.0, a1 = 0.0, a2 = 0.0, a3 = 0.0;
#pragma unroll 2
  for (int j = 0; j < 8; ++j) {
    uint32_t wj = pks[j];
#pragma unroll
    for (int tt = 0; tt < 16; ++tt) {
      int a = (wj >> (2 * tt)) & 3;
      float4 kv = kz[((j * 16 + tt) << 2) + a];
      a0 += (double)kv.x; a1 += (double)kv.y;
      a2 += (double)kv.z; a3 += (double)kv.w;
    }
  }
  uint32_t ib = ((uint32_t)s * 128u + (uint32_t)z) * 4u;  // flat [S,Z,4] index
  double v0 = gumbel32(KZ0, KZ1, ib + 0u) - a0;
  double v1 = gumbel32(KZ0, KZ1, ib + 1u) - a1;
  double v2 = gumbel32(KZ0, KZ1, ib + 2u) - a2;
  double v3 = gumbel32(KZ0, KZ1, ib + 3u) - a3;
  int best = 0; double bv = v0;                 // first-occurrence argmax
  if (v1 > bv) { bv = v1; best = 1; }
  if (v2 > bv) { bv = v2; best = 2; }
  if (v3 > bv) { bv = v3; best = 3; }
  zidxT[(size_t)z * NS + s] = (uint8_t)best;    // coalesced
}

// ---------------- kernel 3: ex + categorical(kx) + loss ----------------
__global__ __launch_bounds__(256) void ex_sample(const float* __restrict__ Kx,
                                                 const uint8_t* __restrict__ zidxT,
                                                 const uint32_t* __restrict__ pk,
                                                 uint8_t* __restrict__ xidx,
                                                 double* __restrict__ loss_acc) {
  int s = blockIdx.x * 256 + threadIdx.x;
  int x = blockIdx.y;
  const float4* kx = (const float4*)Kx + (size_t)x * 512;  // [z][b] float4 over a
  double a0 = 0.0, a1 = 0.0, a2 = 0.0, a3 = 0.0;
#pragma unroll 4
  for (int z = 0; z < 128; ++z) {
    int b = zidxT[(size_t)z * NS + s];          // coalesced byte load
    float4 kv = kx[(z << 2) + b];
    a0 += (double)kv.x; a1 += (double)kv.y;
    a2 += (double)kv.z; a3 += (double)kv.w;
  }
  uint32_t ib = ((uint32_t)s * 128u + (uint32_t)x) * 4u;  // flat [S,X,4] index
  double v0 = gumbel32(KX0, KX1, ib + 0u) - a0;
  double v1 = gumbel32(KX0, KX1, ib + 1u) - a1;
  double v2 = gumbel32(KX0, KX1, ib + 2u) - a2;
  double v3 = gumbel32(KX0, KX1, ib + 3u) - a3;
  int best = 0; double bv = v0;
  if (v1 > bv) { bv = v1; best = 1; }
  if (v2 > bv) { bv = v2; best = 2; }
  if (v3 > bv) { bv = v3; best = 3; }
  xidx[(size_t)s * 128 + x] = (uint8_t)best;

  // loss term: ex[a0_idx] - ex[sampled]
  uint32_t wj = pk[(size_t)s * 8 + (x >> 4)];
  int ai = (wj >> (2 * (x & 15))) & 3;
  double exa = (ai == 0) ? a0 : (ai == 1) ? a1 : (ai == 2) ? a2 : a3;
  double exi = (best == 0) ? a0 : (best == 1) ? a1 : (best == 2) ? a2 : a3;
  double term = exa - exi;

  // wave (64) + block reduce, one f64 atomic per block
#pragma unroll
  for (int off = 32; off > 0; off >>= 1) term += __shfl_down(term, off, 64);
  __shared__ double red[4];
  int wid = threadIdx.x >> 6;
  if ((threadIdx.x & 63) == 0) red[wid] = term;
  __syncthreads();
  if (threadIdx.x == 0) atomicAdd(loss_acc, red[0] + red[1] + red[2] + red[3]);
}

// ---------------- kernel 4: coalesced one-hot writeback + loss ----------------
__global__ __launch_bounds__(256) void write_out(const uint8_t* __restrict__ xidx,
                                                 const double* __restrict__ loss_acc,
                                                 float* __restrict__ out) {
  uint32_t j = blockIdx.x * 256u + threadIdx.x;   // 0 .. 2^25-1
  uint8_t xi = xidx[j >> 2];
  out[1 + j] = ((j & 3u) == (uint32_t)xi) ? 1.0f : 0.0f;
  if (j == 0) out[0] = (float)(*loss_acc * (1.0 / 65536.0));
}

extern "C" void kernel_launch(void* const* d_in, const int* in_sizes, int n_in,
                              void* d_out, int out_size, void* d_ws, size_t ws_size,
                              hipStream_t stream) {
  const float* biadj = (const float*)d_in[0];   // [64,64,8]
  const float* eps   = (const float*)d_in[1];   // [8,3,2,2]
  const float* chi   = (const float*)d_in[2];   // [4,4,3]
  const int*   x0    = (const int*)d_in[3];     // [65536,128]
  float* out = (float*)d_out;                   // [1 + 65536*128*4]

  // workspace layout (~20 MB)
  double*   loss_acc = (double*)d_ws;
  float*    Kz    = (float*)((char*)d_ws + 256);        // 1 MB
  float*    Kx    = Kz + 128 * 128 * 16;                // 1 MB
  uint32_t* pk    = (uint32_t*)(Kx + 128 * 128 * 16);   // 2 MB
  uint8_t*  zidxT = (uint8_t*)(pk + (size_t)NS * 8);    // 8 MB
  uint8_t*  xidx  = zidxT + (size_t)NS * ZD;            // 8 MB

  pack_x0<<<NS * 8 / 256, 256, 0, stream>>>(x0, pk, loss_acc);
  build_k<<<64, 256, 0, stream>>>(biadj, eps, chi, Kz, Kx);
  ez_sample<<<dim3(NS / 256, ZD), 256, 0, stream>>>(Kz, pk, zidxT);
  ex_sample<<<dim3(NS / 256, XD), 256, 0, stream>>>(Kx, zidxT, pk, xidx, loss_acc);
  write_out<<<(uint32_t)NS * XD * 4 / 256, 256, 0, stream>>>(xidx, loss_acc, out);
}

// Round 2
// 936.914 us; speedup vs baseline: 1.5565x; 1.5565x over previous
//
#include <hip/hip_runtime.h>
#include <stdint.h>

// Problem constants (from reference)
#define NS   65536    // SAMPLES
#define XD   128      // LX*DX
#define ZD   128      // LZ*DZ
// n states = 4

// ---------------- threefry2x32 (exact JAX semantics) ----------------
struct U2 { uint32_t x, y; };

__host__ __device__ constexpr uint32_t rotl32(uint32_t v, int r) {
  return (v << r) | (v >> (32 - r));
}

__host__ __device__ constexpr U2 threefry2x32(uint32_t k0, uint32_t k1,
                                              uint32_t x0, uint32_t x1) {
  uint32_t ks0 = k0, ks1 = k1, ks2 = k0 ^ k1 ^ 0x1BD11BDAu;
  x0 += ks0; x1 += ks1;
  x0 += x1; x1 = rotl32(x1, 13); x1 ^= x0;
  x0 += x1; x1 = rotl32(x1, 15); x1 ^= x0;
  x0 += x1; x1 = rotl32(x1, 26); x1 ^= x0;
  x0 += x1; x1 = rotl32(x1,  6); x1 ^= x0;
  x0 += ks1; x1 += ks2 + 1u;
  x0 += x1; x1 = rotl32(x1, 17); x1 ^= x0;
  x0 += x1; x1 = rotl32(x1, 29); x1 ^= x0;
  x0 += x1; x1 = rotl32(x1, 16); x1 ^= x0;
  x0 += x1; x1 = rotl32(x1, 24); x1 ^= x0;
  x0 += ks2; x1 += ks0 + 2u;
  x0 += x1; x1 = rotl32(x1, 13); x1 ^= x0;
  x0 += x1; x1 = rotl32(x1, 15); x1 ^= x0;
  x0 += x1; x1 = rotl32(x1, 26); x1 ^= x0;
  x0 += x1; x1 = rotl32(x1,  6); x1 ^= x0;
  x0 += ks0; x1 += ks1 + 3u;
  x0 += x1; x1 = rotl32(x1, 17); x1 ^= x0;
  x0 += x1; x1 = rotl32(x1, 29); x1 ^= x0;
  x0 += x1; x1 = rotl32(x1, 16); x1 ^= x0;
  x0 += x1; x1 = rotl32(x1, 24); x1 ^= x0;
  x0 += ks1; x1 += ks2 + 4u;
  x0 += x1; x1 = rotl32(x1, 13); x1 ^= x0;
  x0 += x1; x1 = rotl32(x1, 15); x1 ^= x0;
  x0 += x1; x1 = rotl32(x1, 26); x1 ^= x0;
  x0 += x1; x1 = rotl32(x1,  6); x1 ^= x0;
  x0 += ks2; x1 += ks0 + 5u;
  return {x0, x1};
}

constexpr U2 KEYZ = threefry2x32(0u, 42u, 0u, 0u);
constexpr U2 KEYX = threefry2x32(0u, 42u, 0u, 1u);
constexpr uint32_t KZ0 = KEYZ.x, KZ1 = KEYZ.y;
constexpr uint32_t KX0 = KEYX.x, KX1 = KEYX.y;

__device__ inline double gumbel32(uint32_t k0, uint32_t k1, uint32_t idx) {
  U2 h = threefry2x32(k0, k1, 0u, idx);
  uint32_t bits = h.x ^ h.y;
  float f = __uint_as_float((bits >> 9) | 0x3f800000u) - 1.0f;  // [0,1)
  float u = (f == 0.0f) ? 1.1754943508222875e-38f : f;          // max(tiny, .)
  double lu = log((double)u);
  return -log(-lu);
}

// ---------------- kernel 0: pack x0_idx to 2-bit codes, zero loss ----------------
__global__ __launch_bounds__(256) void pack_x0(const int* __restrict__ x0,
                                               uint32_t* __restrict__ pk,
                                               double* __restrict__ loss_acc) {
  int t = blockIdx.x * 256 + threadIdx.x;   // 0 .. NS*8-1
  if (t == 0) *loss_acc = 0.0;
  const int4* src = (const int4*)x0 + (size_t)t * 4;  // 16 consecutive ints
  uint32_t w = 0;
#pragma unroll
  for (int i = 0; i < 4; ++i) {
    int4 v = src[i];
    w |= (uint32_t)(v.x & 3) << (8 * i + 0);
    w |= (uint32_t)(v.y & 3) << (8 * i + 2);
    w |= (uint32_t)(v.z & 3) << (8 * i + 4);
    w |= (uint32_t)(v.w & 3) << (8 * i + 6);
  }
  pk[t] = w;
}

// ---------------- kernel 1: K in two layouts (f32, same rounding as round 1) ----
// Kz[z][x][a][b], Kx[x][z][b][a]
__global__ __launch_bounds__(256) void build_k(const float* __restrict__ biadj,
                                               const float* __restrict__ eps,
                                               const float* __restrict__ chi,
                                               float* __restrict__ Kz,
                                               float* __restrict__ Kx) {
  int t = blockIdx.x * 256 + threadIdx.x;  // 0..16383
  int xx = t >> 7, zz = t & 127;
  int ix = xx >> 1, dx = xx & 1;
  int iz = zz >> 1, dz = zz & 1;
  double c0 = 0.0, c1 = 0.0, c2 = 0.0;
#pragma unroll
  for (int b = 0; b < 8; ++b) {
    double bi = (double)biadj[(ix * 64 + iz) * 8 + b];
    c0 += bi * (double)eps[((b * 3 + 0) * 2 + dx) * 2 + dz];
    c1 += bi * (double)eps[((b * 3 + 1) * 2 + dx) * 2 + dz];
    c2 += bi * (double)eps[((b * 3 + 2) * 2 + dx) * 2 + dz];
  }
#pragma unroll
  for (int p = 0; p < 4; ++p)
#pragma unroll
    for (int q = 0; q < 4; ++q) {
      double kv = c0 * (double)chi[(p * 4 + q) * 3 + 0]
                + c1 * (double)chi[(p * 4 + q) * 3 + 1]
                + c2 * (double)chi[(p * 4 + q) * 3 + 2];
      float kf = (float)kv;
      Kz[((zz * 128 + xx) * 4 + p) * 4 + q] = kf;
      Kx[((xx * 128 + zz) * 4 + q) * 4 + p] = kf;
    }
}

// ---------------- kernel 2: exact f64 pair-sum tables ----------------
// PZ[z][xp][half][c] (double2): comps b; entry = Kz[z][2xp][c&3][:] + Kz[z][2xp+1][c>>2][:]
// PX[x][zp][half][c] (double2): comps a; entry = Kx[x][2zp][c&3][:] + Kx[x][2zp+1][c>>2][:]
__global__ __launch_bounds__(256) void build_pairs(const float* __restrict__ Kz,
                                                   const float* __restrict__ Kx,
                                                   double2* __restrict__ PZ,
                                                   double2* __restrict__ PX) {
  int gid = blockIdx.x * 256 + threadIdx.x;   // 0 .. 262143
  int isX = gid >> 17;                         // 0: PZ, 1: PX
  int t = gid & 131071;
  int c = t & 15, rp = (t >> 4) & 63, r = t >> 10;   // r = z or x
  const float4* K4 = (const float4*)(isX ? Kx : Kz);
  float4 kA = K4[(r * 128 + 2 * rp) * 4 + (c & 3)];
  float4 kB = K4[(r * 128 + 2 * rp + 1) * 4 + (c >> 2)];
  double2* P = isX ? PX : PZ;
  int idx = (r * 64 + rp) * 32 + c;
  P[idx]      = double2{ (double)kA.x + (double)kB.x, (double)kA.y + (double)kB.y };
  P[idx + 16] = double2{ (double)kA.z + (double)kB.z, (double)kA.w + (double)kB.w };
}

// ---------------- shared gather core (pair LDS table) ----------------
// acc[4] += sum over 64 pairs of table[pair][code]
__device__ inline void pair_accum(const double2* __restrict__ L,
                                  const uint32_t* __restrict__ codes, int stride,
                                  double& a0, double& a1, double& a2, double& a3) {
#pragma unroll
  for (int j = 0; j < 8; ++j) {
    uint32_t w = codes[(size_t)j * stride];
#pragma unroll
    for (int t = 0; t < 8; ++t) {
      int c = (w >> (4 * t)) & 15;
      int idx = (8 * j + t) * 32 + c;
      double2 e0 = L[idx];
      double2 e1 = L[idx + 16];
      a0 += e0.x; a1 += e0.y; a2 += e1.x; a3 += e1.y;
    }
  }
}

// ---------------- kernel 3: ez + categorical(kz) -> zidxT[z][s] ----------------
__global__ __launch_bounds__(256) void ez_pair(const double2* __restrict__ PZ,
                                               const uint32_t* __restrict__ pk,
                                               uint8_t* __restrict__ zidxT) {
  __shared__ double2 Ltab[2048];   // 32 KB
  int tid = threadIdx.x;
  int z = blockIdx.y;
  {  // stage this z's table: 2048 double2 = 2048 uint4
    const uint4* src = (const uint4*)(PZ + (size_t)z * 2048);
    uint4* dst = (uint4*)Ltab;
#pragma unroll
    for (int i = 0; i < 8; ++i) dst[tid + i * 256] = src[tid + i * 256];
  }
  __syncthreads();
  int s = blockIdx.x * 256 + tid;
  double a0 = 0.0, a1 = 0.0, a2 = 0.0, a3 = 0.0;
  pair_accum(Ltab, pk + (size_t)s * 8, 1, a0, a1, a2, a3);

  uint32_t ib = ((uint32_t)s * 128u + (uint32_t)z) * 4u;
  double v0 = gumbel32(KZ0, KZ1, ib + 0u) - a0;
  double v1 = gumbel32(KZ0, KZ1, ib + 1u) - a1;
  double v2 = gumbel32(KZ0, KZ1, ib + 2u) - a2;
  double v3 = gumbel32(KZ0, KZ1, ib + 3u) - a3;
  int best = 0; double bv = v0;
  if (v1 > bv) { bv = v1; best = 1; }
  if (v2 > bv) { bv = v2; best = 2; }
  if (v3 > bv) { bv = v3; best = 3; }
  zidxT[(size_t)z * NS + s] = (uint8_t)best;    // coalesced
}

// ---------------- kernel 4: repack zidx bytes -> 2-bit codes zpk[j][s] --------
__global__ __launch_bounds__(256) void repack_z(const uint8_t* __restrict__ zidxT,
                                                uint32_t* __restrict__ zpk) {
  uint32_t t = blockIdx.x * 256u + threadIdx.x;  // 0 .. NS*8-1
  uint32_t j = t >> 16, s = t & 65535u;
  uint32_t w = 0;
#pragma unroll
  for (int k = 0; k < 16; ++k)
    w |= (uint32_t)zidxT[(size_t)(16 * j + k) * NS + s] << (2 * k);
  zpk[t] = w;   // zpk[j*NS + s], coalesced
}

// ---------------- kernel 5: ex + categorical(kx) + loss -> xidxT[x][s] --------
__global__ __launch_bounds__(256) void ex_pair(const double2* __restrict__ PX,
                                               const uint32_t* __restrict__ zpk,
                                               const uint32_t* __restrict__ pk,
                                               uint8_t* __restrict__ xidxT,
                                               double* __restrict__ loss_acc) {
  __shared__ double2 Ltab[2048];   // 32 KB
  __shared__ double red[4];
  int tid = threadIdx.x;
  int x = blockIdx.y;
  {
    const uint4* src = (const uint4*)(PX + (size_t)x * 2048);
    uint4* dst = (uint4*)Ltab;
#pragma unroll
    for (int i = 0; i < 8; ++i) dst[tid + i * 256] = src[tid + i * 256];
  }
  __syncthreads();
  int s = blockIdx.x * 256 + tid;
  double a0 = 0.0, a1 = 0.0, a2 = 0.0, a3 = 0.0;
  pair_accum(Ltab, zpk + s, NS, a0, a1, a2, a3);

  uint32_t ib = ((uint32_t)s * 128u + (uint32_t)x) * 4u;
  double v0 = gumbel32(KX0, KX1, ib + 0u) - a0;
  double v1 = gumbel32(KX0, KX1, ib + 1u) - a1;
  double v2 = gumbel32(KX0, KX1, ib + 2u) - a2;
  double v3 = gumbel32(KX0, KX1, ib + 3u) - a3;
  int best = 0; double bv = v0;
  if (v1 > bv) { bv = v1; best = 1; }
  if (v2 > bv) { bv = v2; best = 2; }
  if (v3 > bv) { bv = v3; best = 3; }
  xidxT[(size_t)x * NS + s] = (uint8_t)best;    // coalesced

  // loss term: ex[x0_code] - ex[sampled]
  uint32_t wj = pk[(size_t)s * 8 + (x >> 4)];
  int ai = (wj >> (2 * (x & 15))) & 3;
  double exa = (ai == 0) ? a0 : (ai == 1) ? a1 : (ai == 2) ? a2 : a3;
  double exi = (best == 0) ? a0 : (best == 1) ? a1 : (best == 2) ? a2 : a3;
  double term = exa - exi;
#pragma unroll
  for (int off = 32; off > 0; off >>= 1) term += __shfl_down(term, off, 64);
  int wid = tid >> 6;
  if ((tid & 63) == 0) red[wid] = term;
  __syncthreads();
  if (tid == 0) atomicAdd(loss_acc, red[0] + red[1] + red[2] + red[3]);
}

// ---------------- kernel 6: fused transpose + one-hot writeback + loss --------
// reads xidxT[x][s] through an LDS tile, writes out[1 + (s*128+x)*4 + c] coalesced
__global__ __launch_bounds__(256) void write_out(const uint8_t* __restrict__ xidxT,
                                                 const double* __restrict__ loss_acc,
                                                 float* __restrict__ out) {
  __shared__ uint8_t tile[128 * 80];   // [x][s0..s0+63], stride 80
  int tid = threadIdx.x;
  int s0 = blockIdx.x * 64;
  {  // stage 128 x-rows of 64 s-bytes
    int x = tid >> 1, chunk = tid & 1;
    const uint8_t* src = xidxT + (size_t)x * NS + s0 + chunk * 32;
    uint4 v0 = *(const uint4*)(src);
    uint4 v1 = *(const uint4*)(src + 16);
    *(uint4*)&tile[x * 80 + chunk * 32 + 0]  = v0;
    *(uint4*)&tile[x * 80 + chunk * 32 + 16] = v1;
  }
  __syncthreads();
  float* dst = out + 1 + (size_t)s0 * 512;
#pragma unroll 4
  for (int k = 0; k < 128; ++k) {
    int f = k * 256 + tid;               // 0 .. 32767 within block tile
    int c = f & 3, x = (f >> 2) & 127, sl = f >> 9;
    uint8_t b = tile[x * 80 + sl];
    dst[f] = (c == (int)b) ? 1.0f : 0.0f;   // contiguous per k-iteration
  }
  if (blockIdx.x == 0 && tid == 0) out[0] = (float)(*loss_acc * (1.0 / 65536.0));
}

extern "C" void kernel_launch(void* const* d_in, const int* in_sizes, int n_in,
                              void* d_out, int out_size, void* d_ws, size_t ws_size,
                              hipStream_t stream) {
  const float* biadj = (const float*)d_in[0];   // [64,64,8]
  const float* eps   = (const float*)d_in[1];   // [8,3,2,2]
  const float* chi   = (const float*)d_in[2];   // [4,4,3]
  const int*   x0    = (const int*)d_in[3];     // [65536,128]
  float* out = (float*)d_out;                   // [1 + 65536*128*4]

  // workspace layout (~30.25 MB)
  char* w = (char*)d_ws;
  double*   loss_acc = (double*)w;                 w += 256;
  float*    Kz    = (float*)w;                     w += (size_t)128 * 128 * 16 * 4;  // 1 MB
  float*    Kx    = (float*)w;                     w += (size_t)128 * 128 * 16 * 4;  // 1 MB
  uint32_t* pk    = (uint32_t*)w;                  w += (size_t)NS * 8 * 4;          // 2 MB
  uint8_t*  zidxT = (uint8_t*)w;                   w += (size_t)NS * ZD;             // 8 MB
  uint32_t* zpk   = (uint32_t*)w;                  w += (size_t)NS * 8 * 4;          // 2 MB
  uint8_t*  xidxT = (uint8_t*)w;                   w += (size_t)NS * XD;             // 8 MB
  double2*  PZ    = (double2*)w;                   w += (size_t)128 * 64 * 32 * 16;  // 4 MB
  double2*  PX    = (double2*)w;                   /* 4 MB */

  pack_x0<<<NS * 8 / 256, 256, 0, stream>>>(x0, pk, loss_acc);
  build_k<<<64, 256, 0, stream>>>(biadj, eps, chi, Kz, Kx);
  build_pairs<<<1024, 256, 0, stream>>>(Kz, Kx, PZ, PX);
  ez_pair<<<dim3(NS / 256, ZD), 256, 0, stream>>>(PZ, pk, zidxT);
  repack_z<<<NS * 8 / 256, 256, 0, stream>>>(zidxT, zpk);
  ex_pair<<<dim3(NS / 256, XD), 256, 0, stream>>>(PX, zpk, pk, xidxT, loss_acc);
  write_out<<<NS / 64, 256, 0, stream>>>(xidxT, loss_acc, out);
}

// Round 3
// 731.693 us; speedup vs baseline: 1.9931x; 1.2805x over previous
//
#include <hip/hip_runtime.h>
#include <stdint.h>

// Problem constants (from reference)
#define NS   65536    // SAMPLES
#define XD   128      // LX*DX
#define ZD   128      // LZ*DZ
// n states = 4

// ---------------- threefry2x32 (exact JAX semantics) ----------------
struct U2 { uint32_t x, y; };

__host__ __device__ constexpr uint32_t rotl32(uint32_t v, int r) {
  return (v << r) | (v >> (32 - r));
}

__host__ __device__ constexpr U2 threefry2x32(uint32_t k0, uint32_t k1,
                                              uint32_t x0, uint32_t x1) {
  uint32_t ks0 = k0, ks1 = k1, ks2 = k0 ^ k1 ^ 0x1BD11BDAu;
  x0 += ks0; x1 += ks1;
  x0 += x1; x1 = rotl32(x1, 13); x1 ^= x0;
  x0 += x1; x1 = rotl32(x1, 15); x1 ^= x0;
  x0 += x1; x1 = rotl32(x1, 26); x1 ^= x0;
  x0 += x1; x1 = rotl32(x1,  6); x1 ^= x0;
  x0 += ks1; x1 += ks2 + 1u;
  x0 += x1; x1 = rotl32(x1, 17); x1 ^= x0;
  x0 += x1; x1 = rotl32(x1, 29); x1 ^= x0;
  x0 += x1; x1 = rotl32(x1, 16); x1 ^= x0;
  x0 += x1; x1 = rotl32(x1, 24); x1 ^= x0;
  x0 += ks2; x1 += ks0 + 2u;
  x0 += x1; x1 = rotl32(x1, 13); x1 ^= x0;
  x0 += x1; x1 = rotl32(x1, 15); x1 ^= x0;
  x0 += x1; x1 = rotl32(x1, 26); x1 ^= x0;
  x0 += x1; x1 = rotl32(x1,  6); x1 ^= x0;
  x0 += ks0; x1 += ks1 + 3u;
  x0 += x1; x1 = rotl32(x1, 17); x1 ^= x0;
  x0 += x1; x1 = rotl32(x1, 29); x1 ^= x0;
  x0 += x1; x1 = rotl32(x1, 16); x1 ^= x0;
  x0 += x1; x1 = rotl32(x1, 24); x1 ^= x0;
  x0 += ks1; x1 += ks2 + 4u;
  x0 += x1; x1 = rotl32(x1, 13); x1 ^= x0;
  x0 += x1; x1 = rotl32(x1, 15); x1 ^= x0;
  x0 += x1; x1 = rotl32(x1, 26); x1 ^= x0;
  x0 += x1; x1 = rotl32(x1,  6); x1 ^= x0;
  x0 += ks2; x1 += ks0 + 5u;
  return {x0, x1};
}

constexpr U2 KEYZ = threefry2x32(0u, 42u, 0u, 0u);
constexpr U2 KEYX = threefry2x32(0u, 42u, 0u, 1u);
constexpr uint32_t KZ0 = KEYZ.x, KZ1 = KEYZ.y;
constexpr uint32_t KX0 = KEYX.x, KX1 = KEYX.y;

// f32 gumbel (same as jax's own f32 path; np-f64 ref differs by ~1e-7 abs)
__device__ inline float gumbel32f(uint32_t k0, uint32_t k1, uint32_t idx) {
  U2 h = threefry2x32(k0, k1, 0u, idx);
  uint32_t bits = h.x ^ h.y;
  float f = __uint_as_float((bits >> 9) | 0x3f800000u) - 1.0f;  // [0,1)
  float u = fmaxf(f, 1.1754943508222875e-38f);
  float lu = __logf(u);          // < 0
  return -__logf(-lu);
}

// ---------------- kernel 0: pack x0_idx to 2-bit codes, zero loss ----------------
__global__ __launch_bounds__(256) void pack_x0(const int* __restrict__ x0,
                                               uint32_t* __restrict__ pk,
                                               double* __restrict__ loss_acc) {
  int t = blockIdx.x * 256 + threadIdx.x;   // 0 .. NS*8-1
  if (t == 0) *loss_acc = 0.0;
  const int4* src = (const int4*)x0 + (size_t)t * 4;  // 16 consecutive ints
  uint32_t w = 0;
#pragma unroll
  for (int i = 0; i < 4; ++i) {
    int4 v = src[i];
    w |= (uint32_t)(v.x & 3) << (8 * i + 0);
    w |= (uint32_t)(v.y & 3) << (8 * i + 2);
    w |= (uint32_t)(v.z & 3) << (8 * i + 4);
    w |= (uint32_t)(v.w & 3) << (8 * i + 6);
  }
  pk[t] = w;
}

// ---------------- kernel 1: K in two layouts (f32) ----------------
// Kz[z][x][a][b], Kx[x][z][b][a]
__global__ __launch_bounds__(256) void build_k(const float* __restrict__ biadj,
                                               const float* __restrict__ eps,
                                               const float* __restrict__ chi,
                                               float* __restrict__ Kz,
                                               float* __restrict__ Kx) {
  int t = blockIdx.x * 256 + threadIdx.x;  // 0..16383
  int xx = t >> 7, zz = t & 127;
  int ix = xx >> 1, dx = xx & 1;
  int iz = zz >> 1, dz = zz & 1;
  double c0 = 0.0, c1 = 0.0, c2 = 0.0;
#pragma unroll
  for (int b = 0; b < 8; ++b) {
    double bi = (double)biadj[(ix * 64 + iz) * 8 + b];
    c0 += bi * (double)eps[((b * 3 + 0) * 2 + dx) * 2 + dz];
    c1 += bi * (double)eps[((b * 3 + 1) * 2 + dx) * 2 + dz];
    c2 += bi * (double)eps[((b * 3 + 2) * 2 + dx) * 2 + dz];
  }
#pragma unroll
  for (int p = 0; p < 4; ++p)
#pragma unroll
    for (int q = 0; q < 4; ++q) {
      double kv = c0 * (double)chi[(p * 4 + q) * 3 + 0]
                + c1 * (double)chi[(p * 4 + q) * 3 + 1]
                + c2 * (double)chi[(p * 4 + q) * 3 + 2];
      float kf = (float)kv;
      Kz[((zz * 128 + xx) * 4 + p) * 4 + q] = kf;
      Kx[((xx * 128 + zz) * 4 + q) * 4 + p] = kf;
    }
}

// ---------------- kernel 2: f32 pair-sum tables (float4 entries) ----------------
// PZ[z][pair][code] float4 over comps-b; PX[x][pair][code] float4 over comps-a
// entry = K4[r][2p][c&3] + K4[r][2p+1][c>>2]  (f32 add; err ~ulp, << jax's own)
__global__ __launch_bounds__(256) void build_pairs(const float* __restrict__ Kz,
                                                   const float* __restrict__ Kx,
                                                   float4* __restrict__ PZ,
                                                   float4* __restrict__ PX) {
  int gid = blockIdx.x * 256 + threadIdx.x;   // 0 .. 262143
  int isX = gid >> 17;                         // 0: PZ, 1: PX
  int t = gid & 131071;
  int c = t & 15, rp = (t >> 4) & 63, r = t >> 10;   // r = z or x
  const float4* K4 = (const float4*)(isX ? Kx : Kz);
  float4 kA = K4[(r * 128 + 2 * rp) * 4 + (c & 3)];
  float4 kB = K4[(r * 128 + 2 * rp + 1) * 4 + (c >> 2)];
  float4* P = isX ? PX : PZ;
  P[(r * 64 + rp) * 16 + c] =
      float4{kA.x + kB.x, kA.y + kB.y, kA.z + kB.z, kA.w + kB.w};
}

// ---------------- shared gather core ----------------
// f32 accumulation within 16-pair groups, f64 across the 4 groups.
// codes: 8 uint32 words (4-bit code per pair), word j at codes[j*stride].
template <int STRIDE>
__device__ inline void pair_accum(const float4* __restrict__ L,
                                  const uint32_t* __restrict__ codes,
                                  double& d0, double& d1, double& d2, double& d3) {
#pragma unroll
  for (int g = 0; g < 4; ++g) {
    float g0 = 0.f, g1 = 0.f, g2 = 0.f, g3 = 0.f;
#pragma unroll
    for (int j2 = 0; j2 < 2; ++j2) {
      uint32_t w = codes[(size_t)(2 * g + j2) * STRIDE];
#pragma unroll
      for (int t = 0; t < 8; ++t) {
        int c = (w >> (4 * t)) & 15;
        float4 e = L[(16 * g + 8 * j2 + t) * 16 + c];
        g0 += e.x; g1 += e.y; g2 += e.z; g3 += e.w;
      }
    }
    d0 += (double)g0; d1 += (double)g1; d2 += (double)g2; d3 += (double)g3;
  }
}

// ---------------- kernel 3: ez + categorical(kz) -> zidxT[z][s] ----------------
__global__ __launch_bounds__(256) void ez_pair(const float4* __restrict__ PZ,
                                               const uint32_t* __restrict__ pk,
                                               uint8_t* __restrict__ zidxT) {
  __shared__ float4 Ltab[1024];   // 16 KB
  int tid = threadIdx.x;
  int z = blockIdx.y;
  {  // stage this z's table: 1024 float4
    const uint4* src = (const uint4*)(PZ + (size_t)z * 1024);
    uint4* dst = (uint4*)Ltab;
#pragma unroll
    for (int i = 0; i < 4; ++i) dst[tid + i * 256] = src[tid + i * 256];
  }
  __syncthreads();
  int s = blockIdx.x * 256 + tid;
  uint32_t cw[8];
  {  // two 16B loads of this sample's codes
    uint4 w0 = *(const uint4*)(pk + (size_t)s * 8);
    uint4 w1 = *(const uint4*)(pk + (size_t)s * 8 + 4);
    cw[0] = w0.x; cw[1] = w0.y; cw[2] = w0.z; cw[3] = w0.w;
    cw[4] = w1.x; cw[5] = w1.y; cw[6] = w1.z; cw[7] = w1.w;
  }
  double d0 = 0.0, d1 = 0.0, d2 = 0.0, d3 = 0.0;
  pair_accum<1>(Ltab, cw, d0, d1, d2, d3);

  uint32_t ib = ((uint32_t)s * 128u + (uint32_t)z) * 4u;
  double v0 = (double)gumbel32f(KZ0, KZ1, ib + 0u) - d0;
  double v1 = (double)gumbel32f(KZ0, KZ1, ib + 1u) - d1;
  double v2 = (double)gumbel32f(KZ0, KZ1, ib + 2u) - d2;
  double v3 = (double)gumbel32f(KZ0, KZ1, ib + 3u) - d3;
  int best = 0; double bv = v0;
  if (v1 > bv) { bv = v1; best = 1; }
  if (v2 > bv) { bv = v2; best = 2; }
  if (v3 > bv) { bv = v3; best = 3; }
  zidxT[(size_t)z * NS + s] = (uint8_t)best;    // coalesced
}

// ---------------- kernel 4: repack zidx bytes -> 2-bit codes zpk[j][s] --------
__global__ __launch_bounds__(256) void repack_z(const uint8_t* __restrict__ zidxT,
                                                uint32_t* __restrict__ zpk) {
  uint32_t t = blockIdx.x * 256u + threadIdx.x;  // 0 .. NS*8-1
  uint32_t j = t >> 16, s = t & 65535u;
  uint32_t w = 0;
#pragma unroll
  for (int k = 0; k < 16; ++k)
    w |= (uint32_t)zidxT[(size_t)(16 * j + k) * NS + s] << (2 * k);
  zpk[t] = w;   // zpk[j*NS + s], coalesced
}

// ---------------- kernel 5: ex + categorical(kx) + loss -> xidxT[x][s] --------
__global__ __launch_bounds__(256) void ex_pair(const float4* __restrict__ PX,
                                               const uint32_t* __restrict__ zpk,
                                               const uint32_t* __restrict__ pk,
                                               uint8_t* __restrict__ xidxT,
                                               double* __restrict__ loss_acc) {
  __shared__ float4 Ltab[1024];   // 16 KB
  __shared__ double red[4];
  int tid = threadIdx.x;
  int x = blockIdx.y;
  {
    const uint4* src = (const uint4*)(PX + (size_t)x * 1024);
    uint4* dst = (uint4*)Ltab;
#pragma unroll
    for (int i = 0; i < 4; ++i) dst[tid + i * 256] = src[tid + i * 256];
  }
  __syncthreads();
  int s = blockIdx.x * 256 + tid;
  double d0 = 0.0, d1 = 0.0, d2 = 0.0, d3 = 0.0;
  pair_accum<NS>(Ltab, zpk + s, d0, d1, d2, d3);

  uint32_t ib = ((uint32_t)s * 128u + (uint32_t)x) * 4u;
  double v0 = (double)gumbel32f(KX0, KX1, ib + 0u) - d0;
  double v1 = (double)gumbel32f(KX0, KX1, ib + 1u) - d1;
  double v2 = (double)gumbel32f(KX0, KX1, ib + 2u) - d2;
  double v3 = (double)gumbel32f(KX0, KX1, ib + 3u) - d3;
  int best = 0; double bv = v0;
  if (v1 > bv) { bv = v1; best = 1; }
  if (v2 > bv) { bv = v2; best = 2; }
  if (v3 > bv) { bv = v3; best = 3; }
  xidxT[(size_t)x * NS + s] = (uint8_t)best;    // coalesced

  // loss term: ex[x0_code] - ex[sampled]
  uint32_t wj = pk[(size_t)s * 8 + (x >> 4)];
  int ai = (wj >> (2 * (x & 15))) & 3;
  double exa = (ai == 0) ? d0 : (ai == 1) ? d1 : (ai == 2) ? d2 : d3;
  double exi = (best == 0) ? d0 : (best == 1) ? d1 : (best == 2) ? d2 : d3;
  double term = exa - exi;
#pragma unroll
  for (int off = 32; off > 0; off >>= 1) term += __shfl_down(term, off, 64);
  int wid = tid >> 6;
  if ((tid & 63) == 0) red[wid] = term;
  __syncthreads();
  if (tid == 0) atomicAdd(loss_acc, red[0] + red[1] + red[2] + red[3]);
}

// ---------------- kernel 6: fused transpose + one-hot writeback + loss --------
__global__ __launch_bounds__(256) void write_out(const uint8_t* __restrict__ xidxT,
                                                 const double* __restrict__ loss_acc,
                                                 float* __restrict__ out) {
  __shared__ uint8_t tile[128 * 80];   // [x][s0..s0+63], stride 80
  int tid = threadIdx.x;
  int s0 = blockIdx.x * 64;
  {  // stage 128 x-rows of 64 s-bytes
    int x = tid >> 1, chunk = tid & 1;
    const uint8_t* src = xidxT + (size_t)x * NS + s0 + chunk * 32;
    uint4 v0 = *(const uint4*)(src);
    uint4 v1 = *(const uint4*)(src + 16);
    *(uint4*)&tile[x * 80 + chunk * 32 + 0]  = v0;
    *(uint4*)&tile[x * 80 + chunk * 32 + 16] = v1;
  }
  __syncthreads();
  float* dst = out + 1 + (size_t)s0 * 512;
#pragma unroll 4
  for (int k = 0; k < 128; ++k) {
    int f = k * 256 + tid;               // 0 .. 32767 within block tile
    int c = f & 3, x = (f >> 2) & 127, sl = f >> 9;
    uint8_t b = tile[x * 80 + sl];
    dst[f] = (c == (int)b) ? 1.0f : 0.0f;
  }
  if (blockIdx.x == 0 && tid == 0) out[0] = (float)(*loss_acc * (1.0 / 65536.0));
}

extern "C" void kernel_launch(void* const* d_in, const int* in_sizes, int n_in,
                              void* d_out, int out_size, void* d_ws, size_t ws_size,
                              hipStream_t stream) {
  const float* biadj = (const float*)d_in[0];   // [64,64,8]
  const float* eps   = (const float*)d_in[1];   // [8,3,2,2]
  const float* chi   = (const float*)d_in[2];   // [4,4,3]
  const int*   x0    = (const int*)d_in[3];     // [65536,128]
  float* out = (float*)d_out;                   // [1 + 65536*128*4]

  // workspace layout (~26.25 MB)
  char* w = (char*)d_ws;
  double*   loss_acc = (double*)w;                 w += 256;
  float*    Kz    = (float*)w;                     w += (size_t)128 * 128 * 16 * 4;  // 1 MB
  float*    Kx    = (float*)w;                     w += (size_t)128 * 128 * 16 * 4;  // 1 MB
  uint32_t* pk    = (uint32_t*)w;                  w += (size_t)NS * 8 * 4;          // 2 MB
  uint8_t*  zidxT = (uint8_t*)w;                   w += (size_t)NS * ZD;             // 8 MB
  uint32_t* zpk   = (uint32_t*)w;                  w += (size_t)NS * 8 * 4;          // 2 MB
  uint8_t*  xidxT = (uint8_t*)w;                   w += (size_t)NS * XD;             // 8 MB
  float4*   PZ    = (float4*)w;                    w += (size_t)128 * 64 * 16 * 16;  // 2 MB
  float4*   PX    = (float4*)w;                    /* 2 MB */

  pack_x0<<<NS * 8 / 256, 256, 0, stream>>>(x0, pk, loss_acc);
  build_k<<<64, 256, 0, stream>>>(biadj, eps, chi, Kz, Kx);
  build_pairs<<<1024, 256, 0, stream>>>(Kz, Kx, PZ, PX);
  ez_pair<<<dim3(NS / 256, ZD), 256, 0, stream>>>(PZ, pk, zidxT);
  repack_z<<<NS * 8 / 256, 256, 0, stream>>>(zidxT, zpk);
  ex_pair<<<dim3(NS / 256, XD), 256, 0, stream>>>(PX, zpk, pk, xidxT, loss_acc);
  write_out<<<NS / 64, 256, 0, stream>>>(xidxT, loss_acc, out);
}

// Round 5
// 540.449 us; speedup vs baseline: 2.6984x; 1.3539x over previous
//
#include <hip/hip_runtime.h>
#include <stdint.h>

// Problem constants (from reference)
#define NS   65536    // SAMPLES
#define XD   128      // LX*DX
#define ZD   128      // LZ*DZ
// n states = 4

// ---------------- threefry2x32 (exact JAX semantics) ----------------
struct U2 { uint32_t x, y; };

__host__ __device__ constexpr uint32_t rotl32(uint32_t v, int r) {
  return (v << r) | (v >> (32 - r));
}

__host__ __device__ constexpr U2 threefry2x32(uint32_t k0, uint32_t k1,
                                              uint32_t x0, uint32_t x1) {
  uint32_t ks0 = k0, ks1 = k1, ks2 = k0 ^ k1 ^ 0x1BD11BDAu;
  x0 += ks0; x1 += ks1;
  x0 += x1; x1 = rotl32(x1, 13); x1 ^= x0;
  x0 += x1; x1 = rotl32(x1, 15); x1 ^= x0;
  x0 += x1; x1 = rotl32(x1, 26); x1 ^= x0;
  x0 += x1; x1 = rotl32(x1,  6); x1 ^= x0;
  x0 += ks1; x1 += ks2 + 1u;
  x0 += x1; x1 = rotl32(x1, 17); x1 ^= x0;
  x0 += x1; x1 = rotl32(x1, 29); x1 ^= x0;
  x0 += x1; x1 = rotl32(x1, 16); x1 ^= x0;
  x0 += x1; x1 = rotl32(x1, 24); x1 ^= x0;
  x0 += ks2; x1 += ks0 + 2u;
  x0 += x1; x1 = rotl32(x1, 13); x1 ^= x0;
  x0 += x1; x1 = rotl32(x1, 15); x1 ^= x0;
  x0 += x1; x1 = rotl32(x1, 26); x1 ^= x0;
  x0 += x1; x1 = rotl32(x1,  6); x1 ^= x0;
  x0 += ks0; x1 += ks1 + 3u;
  x0 += x1; x1 = rotl32(x1, 17); x1 ^= x0;
  x0 += x1; x1 = rotl32(x1, 29); x1 ^= x0;
  x0 += x1; x1 = rotl32(x1, 16); x1 ^= x0;
  x0 += x1; x1 = rotl32(x1, 24); x1 ^= x0;
  x0 += ks1; x1 += ks2 + 4u;
  x0 += x1; x1 = rotl32(x1, 13); x1 ^= x0;
  x0 += x1; x1 = rotl32(x1, 15); x1 ^= x0;
  x0 += x1; x1 = rotl32(x1, 26); x1 ^= x0;
  x0 += x1; x1 = rotl32(x1,  6); x1 ^= x0;
  x0 += ks2; x1 += ks0 + 5u;
  return {x0, x1};
}

constexpr U2 KEYZ = threefry2x32(0u, 42u, 0u, 0u);
constexpr U2 KEYX = threefry2x32(0u, 42u, 0u, 1u);
constexpr uint32_t KZ0 = KEYZ.x, KZ1 = KEYZ.y;
constexpr uint32_t KX0 = KEYX.x, KX1 = KEYX.y;

// f32 gumbel (same as jax's own f32 path; np-f64 ref differs by ~1e-7 abs)
__device__ inline float gumbel32f(uint32_t k0, uint32_t k1, uint32_t idx) {
  U2 h = threefry2x32(k0, k1, 0u, idx);
  uint32_t bits = h.x ^ h.y;
  float f = __uint_as_float((bits >> 9) | 0x3f800000u) - 1.0f;  // [0,1)
  float u = fmaxf(f, 1.1754943508222875e-38f);
  float lu = __logf(u);          // < 0
  return -__logf(-lu);
}

// ---------------- kernel 0: pack x0_idx to 2-bit codes, zero loss ----------------
__global__ __launch_bounds__(256) void pack_x0(const int* __restrict__ x0,
                                               uint32_t* __restrict__ pk,
                                               double* __restrict__ loss_acc) {
  int t = blockIdx.x * 256 + threadIdx.x;   // 0 .. NS*8-1
  if (t == 0) *loss_acc = 0.0;
  const int4* src = (const int4*)x0 + (size_t)t * 4;  // 16 consecutive ints
  uint32_t w = 0;
#pragma unroll
  for (int i = 0; i < 4; ++i) {
    int4 v = src[i];
    w |= (uint32_t)(v.x & 3) << (8 * i + 0);
    w |= (uint32_t)(v.y & 3) << (8 * i + 2);
    w |= (uint32_t)(v.z & 3) << (8 * i + 4);
    w |= (uint32_t)(v.w & 3) << (8 * i + 6);
  }
  pk[t] = w;
}

// ---------------- kernel 1: K in two layouts (f32) ----------------
// Kz[z][x][a][b], Kx[x][z][b][a]
__global__ __launch_bounds__(256) void build_k(const float* __restrict__ biadj,
                                               const float* __restrict__ eps,
                                               const float* __restrict__ chi,
                                               float* __restrict__ Kz,
                                               float* __restrict__ Kx) {
  int t = blockIdx.x * 256 + threadIdx.x;  // 0..16383
  int xx = t >> 7, zz = t & 127;
  int ix = xx >> 1, dx = xx & 1;
  int iz = zz >> 1, dz = zz & 1;
  double c0 = 0.0, c1 = 0.0, c2 = 0.0;
#pragma unroll
  for (int b = 0; b < 8; ++b) {
    double bi = (double)biadj[(ix * 64 + iz) * 8 + b];
    c0 += bi * (double)eps[((b * 3 + 0) * 2 + dx) * 2 + dz];
    c1 += bi * (double)eps[((b * 3 + 1) * 2 + dx) * 2 + dz];
    c2 += bi * (double)eps[((b * 3 + 2) * 2 + dx) * 2 + dz];
  }
#pragma unroll
  for (int p = 0; p < 4; ++p)
#pragma unroll
    for (int q = 0; q < 4; ++q) {
      double kv = c0 * (double)chi[(p * 4 + q) * 3 + 0]
                + c1 * (double)chi[(p * 4 + q) * 3 + 1]
                + c2 * (double)chi[(p * 4 + q) * 3 + 2];
      float kf = (float)kv;
      Kz[((zz * 128 + xx) * 4 + p) * 4 + q] = kf;
      Kx[((xx * 128 + zz) * 4 + q) * 4 + p] = kf;
    }
}

// ---------------- kernel 2: f32 pair-sum tables (float4 entries) ----------------
// PZ[z][pair][code] float4 over comps-b; PX[x][pair][code] float4 over comps-a
__global__ __launch_bounds__(256) void build_pairs(const float* __restrict__ Kz,
                                                   const float* __restrict__ Kx,
                                                   float4* __restrict__ PZ,
                                                   float4* __restrict__ PX) {
  int gid = blockIdx.x * 256 + threadIdx.x;   // 0 .. 262143
  int isX = gid >> 17;                         // 0: PZ, 1: PX
  int t = gid & 131071;
  int c = t & 15, rp = (t >> 4) & 63, r = t >> 10;   // r = z or x
  const float4* K4 = (const float4*)(isX ? Kx : Kz);
  float4 kA = K4[(r * 128 + 2 * rp) * 4 + (c & 3)];
  float4 kB = K4[(r * 128 + 2 * rp + 1) * 4 + (c >> 2)];
  float4* P = isX ? PX : PZ;
  P[(r * 64 + rp) * 16 + c] =
      float4{kA.x + kB.x, kA.y + kB.y, kA.z + kB.z, kA.w + kB.w};
}

// ---------------- dual-table gather core ----------------
// Two tables resident in LDS. Each table = 64 pairs * 16 codes = 1024 float4
// (16 KB). Table 1 lives at float4-offset +1024 (byte 16384), which folds into
// the ds_read offset immediate -> no extra address math.
// Numerics per table identical to round 3: f32 within 16-pair groups, f64 across.
__device__ inline void pair_accum2(const float4* __restrict__ L,
                                   const uint32_t* __restrict__ cw,
                                   double* __restrict__ dA,   // table 0: dA[0..3]
                                   double* __restrict__ dB) { // table 1: dB[0..3]
#pragma unroll
  for (int g = 0; g < 4; ++g) {
    float a0 = 0.f, a1 = 0.f, a2 = 0.f, a3 = 0.f;
    float b0 = 0.f, b1 = 0.f, b2 = 0.f, b3 = 0.f;
#pragma unroll
    for (int j2 = 0; j2 < 2; ++j2) {
      uint32_t w = cw[2 * g + j2];
#pragma unroll
      for (int t = 0; t < 8; ++t) {
        int c = (w >> (4 * t)) & 15;
        const float4* e = &L[(16 * g + 8 * j2 + t) * 16 + c];
        float4 e0 = e[0];
        float4 e1 = e[1024];          // second table, byte offset 16384
        a0 += e0.x; a1 += e0.y; a2 += e0.z; a3 += e0.w;
        b0 += e1.x; b1 += e1.y; b2 += e1.z; b3 += e1.w;
      }
    }
    dA[0] += (double)a0; dA[1] += (double)a1; dA[2] += (double)a2; dA[3] += (double)a3;
    dB[0] += (double)b0; dB[1] += (double)b1; dB[2] += (double)b2; dB[3] += (double)b3;
  }
}

__device__ inline int argmax4(double v0, double v1, double v2, double v3) {
  int best = 0; double bv = v0;
  if (v1 > bv) { bv = v1; best = 1; }
  if (v2 > bv) { bv = v2; best = 2; }
  if (v3 > bv) { bv = v3; best = 3; }
  return best;
}

// ---------------- kernel 3: ez + categorical(kz) for 2 z's -> zidxT[z][s] ------
__global__ __launch_bounds__(256, 4) void ez_pair(const float4* __restrict__ PZ,
                                                  const uint32_t* __restrict__ pk,
                                                  uint8_t* __restrict__ zidxT) {
  __shared__ float4 Ltab[2048];   // 32 KB: tables for z0=2*by (0..1023), z1=2*by+1 (1024..2047)
  int tid = threadIdx.x;
  int by = blockIdx.y;
  {  // stage both tables: contiguous 2048 float4 = 2048 uint4 from PZ
    const uint4* src = (const uint4*)(PZ + (size_t)by * 2048);
    uint4* dst = (uint4*)Ltab;
#pragma unroll
    for (int i = 0; i < 8; ++i) dst[tid + i * 256] = src[tid + i * 256];
  }
  __syncthreads();
  int s = blockIdx.x * 256 + tid;
  uint32_t cw[8];
  {
    uint4 w0 = *(const uint4*)(pk + (size_t)s * 8);
    uint4 w1 = *(const uint4*)(pk + (size_t)s * 8 + 4);
    cw[0] = w0.x; cw[1] = w0.y; cw[2] = w0.z; cw[3] = w0.w;
    cw[4] = w1.x; cw[5] = w1.y; cw[6] = w1.z; cw[7] = w1.w;
  }
  double dA[4] = {0, 0, 0, 0}, dB[4] = {0, 0, 0, 0};
  pair_accum2(Ltab, cw, dA, dB);

  int z0 = 2 * by, z1 = 2 * by + 1;
  uint32_t ibA = ((uint32_t)s * 128u + (uint32_t)z0) * 4u;
  int bestA = argmax4((double)gumbel32f(KZ0, KZ1, ibA + 0u) - dA[0],
                      (double)gumbel32f(KZ0, KZ1, ibA + 1u) - dA[1],
                      (double)gumbel32f(KZ0, KZ1, ibA + 2u) - dA[2],
                      (double)gumbel32f(KZ0, KZ1, ibA + 3u) - dA[3]);
  uint32_t ibB = ibA + 4u;
  int bestB = argmax4((double)gumbel32f(KZ0, KZ1, ibB + 0u) - dB[0],
                      (double)gumbel32f(KZ0, KZ1, ibB + 1u) - dB[1],
                      (double)gumbel32f(KZ0, KZ1, ibB + 2u) - dB[2],
                      (double)gumbel32f(KZ0, KZ1, ibB + 3u) - dB[3]);
  zidxT[(size_t)z0 * NS + s] = (uint8_t)bestA;   // coalesced
  zidxT[(size_t)z1 * NS + s] = (uint8_t)bestB;   // coalesced
}

// ---------------- kernel 4: repack zidx bytes -> 2-bit codes zpk[j][s] --------
__global__ __launch_bounds__(256) void repack_z(const uint8_t* __restrict__ zidxT,
                                                uint32_t* __restrict__ zpk) {
  uint32_t t = blockIdx.x * 256u + threadIdx.x;  // 0 .. NS*8-1
  uint32_t j = t >> 16, s = t & 65535u;
  uint32_t w = 0;
#pragma unroll
  for (int k = 0; k < 16; ++k)
    w |= (uint32_t)zidxT[(size_t)(16 * j + k) * NS + s] << (2 * k);
  zpk[t] = w;   // zpk[j*NS + s], coalesced
}

// ---------------- kernel 5: ex + categorical(kx) + loss for 2 x's -------------
__global__ __launch_bounds__(256, 4) void ex_pair(const float4* __restrict__ PX,
                                                  const uint32_t* __restrict__ zpk,
                                                  const uint32_t* __restrict__ pk,
                                                  uint8_t* __restrict__ xidxT,
                                                  double* __restrict__ loss_acc) {
  __shared__ float4 Ltab[2048];   // 32 KB: tables for x0=2*by, x1=2*by+1
  __shared__ double red[4];
  int tid = threadIdx.x;
  int by = blockIdx.y;
  {
    const uint4* src = (const uint4*)(PX + (size_t)by * 2048);
    uint4* dst = (uint4*)Ltab;
#pragma unroll
    for (int i = 0; i < 8; ++i) dst[tid + i * 256] = src[tid + i * 256];
  }
  __syncthreads();
  int s = blockIdx.x * 256 + tid;
  uint32_t cw[8];
#pragma unroll
  for (int j = 0; j < 8; ++j) cw[j] = zpk[(size_t)j * NS + s];  // coalesced
  double dA[4] = {0, 0, 0, 0}, dB[4] = {0, 0, 0, 0};
  pair_accum2(Ltab, cw, dA, dB);

  int x0 = 2 * by, x1 = 2 * by + 1;
  uint32_t ibA = ((uint32_t)s * 128u + (uint32_t)x0) * 4u;
  int bestA = argmax4((double)gumbel32f(KX0, KX1, ibA + 0u) - dA[0],
                      (double)gumbel32f(KX0, KX1, ibA + 1u) - dA[1],
                      (double)gumbel32f(KX0, KX1, ibA + 2u) - dA[2],
                      (double)gumbel32f(KX0, KX1, ibA + 3u) - dA[3]);
  uint32_t ibB = ibA + 4u;
  int bestB = argmax4((double)gumbel32f(KX0, KX1, ibB + 0u) - dB[0],
                      (double)gumbel32f(KX0, KX1, ibB + 1u) - dB[1],
                      (double)gumbel32f(KX0, KX1, ibB + 2u) - dB[2],
                      (double)gumbel32f(KX0, KX1, ibB + 3u) - dB[3]);
  xidxT[(size_t)x0 * NS + s] = (uint8_t)bestA;   // coalesced
  xidxT[(size_t)x1 * NS + s] = (uint8_t)bestB;   // coalesced

  // loss terms for both x's: ex[x0_code] - ex[sampled]
  uint32_t wj = pk[(size_t)s * 8 + (x0 >> 4)];   // both x's share this word
  int aiA = (wj >> (2 * (x0 & 15))) & 3;
  int aiB = (wj >> (2 * (x1 & 15))) & 3;
  double term =
      ((aiA == 0) ? dA[0] : (aiA == 1) ? dA[1] : (aiA == 2) ? dA[2] : dA[3]) -
      ((bestA == 0) ? dA[0] : (bestA == 1) ? dA[1] : (bestA == 2) ? dA[2] : dA[3]) +
      ((aiB == 0) ? dB[0] : (aiB == 1) ? dB[1] : (aiB == 2) ? dB[2] : dB[3]) -
      ((bestB == 0) ? dB[0] : (bestB == 1) ? dB[1] : (bestB == 2) ? dB[2] : dB[3]);
#pragma unroll
  for (int off = 32; off > 0; off >>= 1) term += __shfl_down(term, off, 64);
  int wid = tid >> 6;
  if ((tid & 63) == 0) red[wid] = term;
  __syncthreads();
  if (tid == 0) atomicAdd(loss_acc, red[0] + red[1] + red[2] + red[3]);
}

// ---------------- kernel 6: fused transpose + one-hot writeback + loss --------
__global__ __launch_bounds__(256) void write_out(const uint8_t* __restrict__ xidxT,
                                                 const double* __restrict__ loss_acc,
                                                 float* __restrict__ out) {
  __shared__ uint8_t tile[128 * 80];   // [x][s0..s0+63], stride 80
  int tid = threadIdx.x;
  int s0 = blockIdx.x * 64;
  {  // stage 128 x-rows of 64 s-bytes
    int x = tid >> 1, chunk = tid & 1;
    const uint8_t* src = xidxT + (size_t)x * NS + s0 + chunk * 32;
    uint4 v0 = *(const uint4*)(src);
    uint4 v1 = *(const uint4*)(src + 16);
    *(uint4*)&tile[x * 80 + chunk * 32 + 0]  = v0;
    *(uint4*)&tile[x * 80 + chunk * 32 + 16] = v1;
  }
  __syncthreads();
  float* dst = out + 1 + (size_t)s0 * 512;
#pragma unroll 4
  for (int k = 0; k < 128; ++k) {
    int f = k * 256 + tid;               // 0 .. 32767 within block tile
    int c = f & 3, x = (f >> 2) & 127, sl = f >> 9;
    uint8_t b = tile[x * 80 + sl];
    dst[f] = (c == (int)b) ? 1.0f : 0.0f;
  }
  if (blockIdx.x == 0 && tid == 0) out[0] = (float)(*loss_acc * (1.0 / 65536.0));
}

extern "C" void kernel_launch(void* const* d_in, const int* in_sizes, int n_in,
                              void* d_out, int out_size, void* d_ws, size_t ws_size,
                              hipStream_t stream) {
  const float* biadj = (const float*)d_in[0];   // [64,64,8]
  const float* eps   = (const float*)d_in[1];   // [8,3,2,2]
  const float* chi   = (const float*)d_in[2];   // [4,4,3]
  const int*   x0    = (const int*)d_in[3];     // [65536,128]
  float* out = (float*)d_out;                   // [1 + 65536*128*4]

  // workspace layout (~26.25 MB)
  char* w = (char*)d_ws;
  double*   loss_acc = (double*)w;                 w += 256;
  float*    Kz    = (float*)w;                     w += (size_t)128 * 128 * 16 * 4;  // 1 MB
  float*    Kx    = (float*)w;                     w += (size_t)128 * 128 * 16 * 4;  // 1 MB
  uint32_t* pk    = (uint32_t*)w;                  w += (size_t)NS * 8 * 4;          // 2 MB
  uint8_t*  zidxT = (uint8_t*)w;                   w += (size_t)NS * ZD;             // 8 MB
  uint32_t* zpk   = (uint32_t*)w;                  w += (size_t)NS * 8 * 4;          // 2 MB
  uint8_t*  xidxT = (uint8_t*)w;                   w += (size_t)NS * XD;             // 8 MB
  float4*   PZ    = (float4*)w;                    w += (size_t)128 * 64 * 16 * 16;  // 2 MB
  float4*   PX    = (float4*)w;                    /* 2 MB */

  pack_x0<<<NS * 8 / 256, 256, 0, stream>>>(x0, pk, loss_acc);
  build_k<<<64, 256, 0, stream>>>(biadj, eps, chi, Kz, Kx);
  build_pairs<<<1024, 256, 0, stream>>>(Kz, Kx, PZ, PX);
  ez_pair<<<dim3(NS / 256, ZD / 2), 256, 0, stream>>>(PZ, pk, zidxT);
  repack_z<<<NS * 8 / 256, 256, 0, stream>>>(zidxT, zpk);
  ex_pair<<<dim3(NS / 256, XD / 2), 256, 0, stream>>>(PX, zpk, pk, xidxT, loss_acc);
  write_out<<<NS / 64, 256, 0, stream>>>(xidxT, loss_acc, out);
}